// Round 5
// baseline (29.343 us; speedup 1.0000x reference)
//
#include <hip/hip_runtime.h>

#define NPIX 1
#define R_MAX 128

#if __has_builtin(__builtin_amdgcn_exp2f)
__device__ __forceinline__ float fast_exp2(float x) { return __builtin_amdgcn_exp2f(x); }
#else
__device__ __forceinline__ float fast_exp2(float x) {
    float e; asm("v_exp_f32 %0, %1" : "=v"(e) : "v"(x)); return e;
}
#endif

__global__ __launch_bounds__(256, 8) void rbf_kernel(
    const float* __restrict__ centers,   // (I, R, 2)
    const float* __restrict__ covs,      // (I, R, 3)
    const float* __restrict__ amps,      // (I, R)
    const float* __restrict__ grid,      // (P, 2)
    float* __restrict__ out,             // (I, P)
    int R, int P, int blocksPerImage)
{
    // Per-RBF constants, pre-scaled by -0.5*log2(e):
    // q' = x*(sa*x + sc*y + k1) + (y*(sb*y + k2) + k0) ; contrib = amp * exp2(q')
    __shared__ float4 s_c[R_MAX][2];

    const int img   = blockIdx.x / blocksPerImage;
    const int chunk = blockIdx.x % blocksPerImage;
    const int base  = chunk * (256 * NPIX);

    constexpr float S = -0.72134752044448170f;  // -0.5 * log2(e)

    for (int r = threadIdx.x; r < R; r += 256) {
        const float2 cc = *(const float2*)(centers + (size_t)(img * R + r) * 2);
        const float* cv = covs + (size_t)(img * R + r) * 3;
        const float a = cv[0], b = cv[1], c = cv[2];
        const float amp = amps[img * R + r];
        s_c[r][0] = make_float4(a * S, b * S, 2.0f * c * S,
                                -2.0f * (a * cc.x + c * cc.y) * S);
        s_c[r][1] = make_float4(-2.0f * (b * cc.y + c * cc.x) * S,
                                (a * cc.x * cc.x + b * cc.y * cc.y + 2.0f * c * cc.x * cc.y) * S,
                                amp, 0.0f);
    }
    __syncthreads();

    const int p = base + (int)threadIdx.x;
    float2 g = make_float2(0.0f, 0.0f);
    if (p < P) g = *(const float2*)(grid + (size_t)p * 2);
    const float x = g.x, y = g.y;
    float zA = 0.0f, zB = 0.0f;

    #pragma unroll 2
    for (int r = 0; r < R; r += 2) {
        const float4 a0 = s_c[r][0];
        const float4 a1 = s_c[r][1];
        const float4 b0 = s_c[r + 1][0];
        const float4 b1 = s_c[r + 1][1];

        // q = x*(sa*x + sc*y + k1) + (y*(sb*y + k2) + k0)   (depth-3, 5 FMA)
        const float tA1 = fmaf(a0.x, x, fmaf(a0.z, y, a0.w));
        const float tA2 = fmaf(a0.y, y, a1.x);
        const float qA  = fmaf(x, tA1, fmaf(y, tA2, a1.y));

        const float tB1 = fmaf(b0.x, x, fmaf(b0.z, y, b0.w));
        const float tB2 = fmaf(b0.y, y, b1.x);
        const float qB  = fmaf(x, tB1, fmaf(y, tB2, b1.y));

        const float eA = fast_exp2(qA);
        const float eB = fast_exp2(qB);
        zA = fmaf(a1.z, eA, zA);
        zB = fmaf(b1.z, eB, zB);
    }

    if (p < P) {
        constexpr float L2E = 1.4426950408889634f;
        const float z = zA + zB;
        const float e = fast_exp2(-z * L2E);                 // exp(-z)
        out[(size_t)img * P + p] = __builtin_amdgcn_rcpf(1.0f + e);  // sigmoid
    }
}

extern "C" void kernel_launch(void* const* d_in, const int* in_sizes, int n_in,
                              void* d_out, int out_size, void* d_ws, size_t ws_size,
                              hipStream_t stream) {
    const float* centers = (const float*)d_in[0];
    const float* covs    = (const float*)d_in[1];
    const float* amps    = (const float*)d_in[2];
    const float* grid    = (const float*)d_in[3];
    float* out = (float*)d_out;

    const int P = in_sizes[3] / 2;        // grid points (rows*cols)
    const int I = out_size / P;           // images
    const int R = in_sizes[2] / I;        // RBFs per image

    const int bpi = (P + 256 * NPIX - 1) / (256 * NPIX);
    rbf_kernel<<<I * bpi, 256, 0, stream>>>(centers, covs, amps, grid, out, R, P, bpi);
}

// Round 6
// 22.984 us; speedup vs baseline: 1.2767x; 1.2767x over previous
//
#include <hip/hip_runtime.h>

#define R_MAX 128

typedef float v2f __attribute__((ext_vector_type(2)));

#if __has_builtin(__builtin_amdgcn_exp2f)
__device__ __forceinline__ float fast_exp2(float x) { return __builtin_amdgcn_exp2f(x); }
#else
__device__ __forceinline__ float fast_exp2(float x) {
    float e; asm("v_exp_f32 %0, %1" : "=v"(e) : "v"(x)); return e;
}
#endif

// packed fp32 fma: d = a*b + c on 2 lanes-worth of pixels per instruction
__device__ __forceinline__ v2f pk_fma(v2f a, v2f b, v2f c) {
    v2f d;
    asm("v_pk_fma_f32 %0, %1, %2, %3" : "=v"(d) : "v"(a), "v"(b), "v"(c));
    return d;
}

__global__ __launch_bounds__(256) void rbf_kernel(
    const float* __restrict__ centers,   // (I, R, 2)
    const float* __restrict__ covs,      // (I, R, 3)
    const float* __restrict__ amps,      // (I, R)
    const float* __restrict__ grid,      // (P, 2)
    float* __restrict__ out,             // (I, P)
    int R, int P, int blocksPerImage)
{
    // Per-RBF constants duplicated for packed math, pre-scaled by -0.5*log2(e):
    // q' = x*(sa*x + sc*y + k1) + (y*(sb*y + k2) + k0) ; contrib = amp * exp2(q')
    __shared__ float4 s_c[R_MAX][4];   // [0]={sa,sa,sb,sb} [1]={sc,sc,k1,k1} [2]={k2,k2,k0,k0} [3]={amp,amp,amp,amp}

    const int img   = blockIdx.x / blocksPerImage;
    const int chunk = blockIdx.x % blocksPerImage;
    const int base  = chunk * 512;     // 256 threads x 2 pixels

    constexpr float S = -0.72134752044448170f;  // -0.5 * log2(e)

    for (int r = threadIdx.x; r < R; r += 256) {
        const float2 cc = *(const float2*)(centers + (size_t)(img * R + r) * 2);
        const float* cv = covs + (size_t)(img * R + r) * 3;
        const float a = cv[0], b = cv[1], c = cv[2];
        const float amp = amps[img * R + r];
        const float sa = a * S, sb = b * S, sc = 2.0f * c * S;
        const float k1 = -2.0f * (a * cc.x + c * cc.y) * S;
        const float k2 = -2.0f * (b * cc.y + c * cc.x) * S;
        const float k0 = (a * cc.x * cc.x + b * cc.y * cc.y + 2.0f * c * cc.x * cc.y) * S;
        s_c[r][0] = make_float4(sa, sa, sb, sb);
        s_c[r][1] = make_float4(sc, sc, k1, k1);
        s_c[r][2] = make_float4(k2, k2, k0, k0);
        s_c[r][3] = make_float4(amp, amp, amp, amp);
    }
    __syncthreads();

    const int p0 = base + (int)threadIdx.x;
    const int p1 = p0 + 256;
    float2 g0 = make_float2(0.0f, 0.0f), g1 = make_float2(0.0f, 0.0f);
    if (p0 < P) g0 = *(const float2*)(grid + (size_t)p0 * 2);
    if (p1 < P) g1 = *(const float2*)(grid + (size_t)p1 * 2);
    v2f x2 = {g0.x, g1.x}, y2 = {g0.y, g1.y};
    v2f zA = {0.0f, 0.0f}, zB = {0.0f, 0.0f};

    #pragma unroll 2
    for (int r = 0; r < R; r += 2) {
        const float4 a0 = s_c[r][0],     a1 = s_c[r][1],     a2 = s_c[r][2],     a3 = s_c[r][3];
        const float4 b0 = s_c[r + 1][0], b1 = s_c[r + 1][1], b2 = s_c[r + 1][2], b3 = s_c[r + 1][3];

        const v2f saA = {a0.x, a0.y}, sbA = {a0.z, a0.w}, scA = {a1.x, a1.y}, k1A = {a1.z, a1.w};
        const v2f k2A = {a2.x, a2.y}, k0A = {a2.z, a2.w}, amA = {a3.x, a3.y};
        const v2f saB = {b0.x, b0.y}, sbB = {b0.z, b0.w}, scB = {b1.x, b1.y}, k1B = {b1.z, b1.w};
        const v2f k2B = {b2.x, b2.y}, k0B = {b2.z, b2.w}, amB = {b3.x, b3.y};

        // depth-3 Horner, 5 pk-FMA per r for both pixels
        const v2f t1A = pk_fma(saA, x2, pk_fma(scA, y2, k1A));
        const v2f t2A = pk_fma(sbA, y2, k2A);
        const v2f qA  = pk_fma(x2, t1A, pk_fma(y2, t2A, k0A));
        const v2f t1B = pk_fma(saB, x2, pk_fma(scB, y2, k1B));
        const v2f t2B = pk_fma(sbB, y2, k2B);
        const v2f qB  = pk_fma(x2, t1B, pk_fma(y2, t2B, k0B));

        v2f eA, eB;
        eA.x = fast_exp2(qA.x); eA.y = fast_exp2(qA.y);
        eB.x = fast_exp2(qB.x); eB.y = fast_exp2(qB.y);

        zA = pk_fma(amA, eA, zA);
        zB = pk_fma(amB, eB, zB);
    }

    constexpr float L2E = 1.4426950408889634f;
    const v2f z = zA + zB;
    if (p0 < P) out[(size_t)img * P + p0] = __builtin_amdgcn_rcpf(1.0f + fast_exp2(-z.x * L2E));
    if (p1 < P) out[(size_t)img * P + p1] = __builtin_amdgcn_rcpf(1.0f + fast_exp2(-z.y * L2E));
}

extern "C" void kernel_launch(void* const* d_in, const int* in_sizes, int n_in,
                              void* d_out, int out_size, void* d_ws, size_t ws_size,
                              hipStream_t stream) {
    const float* centers = (const float*)d_in[0];
    const float* covs    = (const float*)d_in[1];
    const float* amps    = (const float*)d_in[2];
    const float* grid    = (const float*)d_in[3];
    float* out = (float*)d_out;

    const int P = in_sizes[3] / 2;        // grid points (rows*cols)
    const int I = out_size / P;           // images
    const int R = in_sizes[2] / I;        // RBFs per image

    const int bpi = (P + 511) / 512;      // 2 pixels per thread
    rbf_kernel<<<I * bpi, 256, 0, stream>>>(centers, covs, amps, grid, out, R, P, bpi);
}